// Round 10
// baseline (386.293 us; speedup 1.0000x reference)
//
#include <hip/hip_runtime.h>
#include <math.h>

// Problem constants (from reference)
#define HS    250      // sender hidden
#define HRr   100      // receiver hidden
#define VOC   40       // vocab, EOS = 39
#define TMAX  30       // max message length
#define NCLS  262144   // output classes
#define KS    10       // sender blocks (each owns 25 h-rows = 100 gate rows)
#define RPB   25       // h-rows per sender block
#define NROLE (KS + 1) // 10 senders + 1 receiver
#define GRID_SENDER 256
#define SPIN_CAP   96  // sender primary-poll iterations before shadow probe
#define SPIN_CAP_R 192 // receiver cap

typedef unsigned long long ull;

// ws layout (bytes):
//   primary (XCD-local L2, sc0 ops):
//     PKNH : ull[2][256]   @ ull 0      h exchange, dbuf by parity
//     PKLP : ull[2][400]   @ ull 512    logit partials
//     PKMSG: ull[30*40]    @ ull 1312   message symbols (done bit in tag)
//   WS_SUMS float[64]  @ byte 20096 ; WS_HR float[100] @ byte 20352
//   shadow (LLC sc0 sc1 — R9-proven path, dual-written):
//     PKNHS @ ull 2600, PKLPS @ ull 3112, PKMSGS @ ull 3912
//   CTRL: leader u32 @ byte 40896, role counter u32 @ byte 40900
#define PKNH(wsp, par)  ((ull*)(wsp) + (size_t)(par) * 256)
#define PKLP(wsp, par)  ((ull*)(wsp) + 512 + (size_t)(par) * 400)
#define PKMSG(wsp)      ((ull*)(wsp) + 1312)
#define PKNHS(wsp, par) ((ull*)(wsp) + 2600 + (size_t)(par) * 256)
#define PKLPS(wsp, par) ((ull*)(wsp) + 3112 + (size_t)(par) * 400)
#define PKMSGS(wsp)     ((ull*)(wsp) + 3912)
#define WS_SUMS 5024   // float index
#define WS_HR   5088   // float index
#define CTRL_LEADER(wsp) ((unsigned*)((char*)(wsp) + 40896))
#define CTRL_ROLE(wsp)   ((unsigned*)((char*)(wsp) + 40900))
#define WS_ZERO_BYTES 40912

#define TG(wv) ((unsigned)((wv) >> 32))

__device__ __forceinline__ float sigf(float x) { return 1.f / (1.f + expf(-x)); }
__device__ __forceinline__ float lanebc(float v, int l) {
  return __int_as_float(__builtin_amdgcn_readlane(__float_as_int(v), l));
}
__device__ __forceinline__ ull packtv(unsigned tag, float v) {
  return ((ull)tag << 32) | (ull)__float_as_uint(v);
}
__device__ __forceinline__ float lowf(ull w) { return __uint_as_float((unsigned)w); }

// XCD-local L2 ops (sc0: bypass L1, served by this XCD's shared L2)
__device__ __forceinline__ void st_l2(ull* p, ull v) {
  asm volatile("global_store_dwordx2 %0, %1, off sc0" :: "v"(p), "v"(v) : "memory");
}
__device__ __forceinline__ ull ld_l2(const ull* p) {
  ull r;
  asm volatile("global_load_dwordx2 %0, %1, off sc0\n\t"
               "s_waitcnt vmcnt(0)"
               : "=v"(r) : "v"(p) : "memory");
  return r;
}
// LLC ops (sc0 sc1: bypass L1+L2) — R9-proven exchange path
__device__ __forceinline__ void st_llc(ull* p, ull v) {
  asm volatile("global_store_dwordx2 %0, %1, off sc0 sc1"
               :: "v"(p), "v"(v) : "memory");
}
__device__ __forceinline__ ull ld_llc(const ull* p) {
  ull r;
  asm volatile("global_load_dwordx2 %0, %1, off sc0 sc1\n\t"
               "s_waitcnt vmcnt(0)"
               : "=v"(r) : "v"(p) : "memory");
  return r;
}

// batched 11-word poll, one waitcnt; FLAGS = "sc0" (L2) or "sc0 sc1" (LLC)
#define POLL11(FLAGS)                                                     \
  asm volatile(                                                           \
    "global_load_dwordx2 %0, %11, off " FLAGS "\n\t"                      \
    "global_load_dwordx2 %1, %12, off " FLAGS "\n\t"                      \
    "global_load_dwordx2 %2, %13, off " FLAGS "\n\t"                      \
    "global_load_dwordx2 %3, %14, off " FLAGS "\n\t"                      \
    "global_load_dwordx2 %4, %15, off " FLAGS "\n\t"                      \
    "global_load_dwordx2 %5, %16, off " FLAGS "\n\t"                      \
    "global_load_dwordx2 %6, %17, off " FLAGS "\n\t"                      \
    "global_load_dwordx2 %7, %18, off " FLAGS "\n\t"                      \
    "global_load_dwordx2 %8, %19, off " FLAGS "\n\t"                      \
    "global_load_dwordx2 %9, %20, off " FLAGS "\n\t"                      \
    "global_load_dwordx2 %10, %21, off " FLAGS "\n\t"                     \
    "s_waitcnt vmcnt(0)"                                                  \
    : "=&v"(hw0), "=&v"(hw1), "=&v"(hw2), "=&v"(hw3),                     \
      "=&v"(lw0), "=&v"(lw1), "=&v"(lw2), "=&v"(lw3),                     \
      "=&v"(lw4), "=&v"(lw5), "=&v"(lw6)                                  \
    : "v"(pn0), "v"(pn1), "v"(pn2), "v"(pn3),                             \
      "v"(pl0), "v"(pl1), "v"(pl2), "v"(pl3),                             \
      "v"(pl4), "v"(pl5), "v"(pl6)                                        \
    : "memory")

#define TAGOK()                                                           \
  (TG(hw0) == need && TG(hw1) == need && TG(hw2) == need &&               \
   (!h3v || TG(hw3) == need) &&                                           \
   (!lpact || (TG(lw0) == need && TG(lw1) == need && TG(lw2) == need &&   \
               TG(lw3) == need && TG(lw4) == need && TG(lw5) == need &&   \
               (!l6v || TG(lw6) == need))))

#define SENDER_GATES(P, HV)                                   \
  {                                                           \
    _Pragma("unroll")                                         \
    for (int i = 0; i < 64; i += 4) {                         \
      a0 += whh[i    ] * lanebc(HV, i    );                   \
      a1 += whh[i + 1] * lanebc(HV, i + 1);                   \
      a2 += whh[i + 2] * lanebc(HV, i + 2);                   \
      a3 += whh[i + 3] * lanebc(HV, i + 3);                   \
    }                                                         \
    _Pragma("unroll")                                         \
    for (int i = 0; i < 10; i += 2) {                         \
      a0 += wih[i    ] * lanebc(sv, (P) * 10 + i    );        \
      a1 += wih[i + 1] * lanebc(sv, (P) * 10 + i + 1);        \
    }                                                         \
  }

#define RED(x) ((part[(x)] + part[100 + (x)]) + (part[200 + (x)] + part[300 + (x)]))

// ---- k_sender: roles claimed onto ONE XCD, one block per CU --------------
// 90 KB static LDS forces 1 block/CU (>80 KB = half the 160 KB pool), so
// the 11 workers occupy 11 DISTINCT CUs of the leader XCD — kills the
// co-scheduling confounder (R2/R5) with the proven 512-thr/128-VGPR config
// (kills R3/R6 spill). Exchange: primary sc0 (XCD L2) + shadow sc0sc1
// (LLC, R9-proven). Consumers flip to shadow only on EVIDENCE (shadow has
// data primary lacks, twice) — bounded worst case = R9 + ~20 us.
__global__ __launch_bounds__(512, 2) void k_sender(
    const float* __restrict__ x,
    const float* __restrict__ W_s1,  const float* __restrict__ b_s1,
    const float* __restrict__ gum,
    const float* __restrict__ W_ih1, const float* __restrict__ W_hh1,
    const float* __restrict__ b_ih1, const float* __restrict__ b_hh1,
    const float* __restrict__ W_p,   const float* __restrict__ b_p,
    const float* __restrict__ W_ih2, const float* __restrict__ W_hh2,
    const float* __restrict__ b_ih2, const float* __restrict__ b_hh2,
    float* __restrict__ ws) {
  __shared__ __align__(16) char ldsbuf[92160];   // 90 KB -> 1 block/CU
  float* part = (float*)ldsbuf;                  // 400 f
  float* h0L  = (float*)(ldsbuf + 1600);         // 32 f
  float* hx   = (float*)(ldsbuf + 1728);         // 256 f
  float* lpx  = (float*)(ldsbuf + 2752);         // 400 f
  float* symx = (float*)(ldsbuf + 4352);         // 40 f (receiver)
  int*   doneLp = (int*)(ldsbuf + 4512);         // 1 i  (receiver)
  float* gL   = (float*)(ldsbuf + 4516);         // 400 f (receiver)
  float* hL   = (float*)(ldsbuf + 6116);         // 100 f (receiver)
  __shared__ int roleL;

  const int t0   = threadIdx.x;
  const int lane = t0 & 63;
  const int w    = t0 >> 6;

  // ---- role claim: pin all NROLE workers onto the leader XCD ----
  unsigned xcc;
  asm volatile("s_getreg_b32 %0, hwreg(HW_REG_XCC_ID)" : "=s"(xcc));
  if (t0 == 0) {
    unsigned old = atomicCAS(CTRL_LEADER(ws), 0u, xcc + 1u);
    unsigned leader = (old == 0u) ? xcc : (old - 1u);
    int r = -1;
    if (xcc == leader) {
      unsigned rr = atomicAdd(CTRL_ROLE(ws), 1u);
      if (rr < NROLE) r = (int)rr;
    } else {
      // backfill safety net (normally leader XCD's 32 blocks fill all roles)
      bool filled = false;
      for (int it = 0; it < 16; ++it) {
        __builtin_amdgcn_s_sleep(16);
        if (__hip_atomic_load(CTRL_ROLE(ws), __ATOMIC_RELAXED,
                              __HIP_MEMORY_SCOPE_AGENT) >= NROLE) { filled = true; break; }
      }
      if (!filled) {
        unsigned rr = atomicAdd(CTRL_ROLE(ws), 1u);
        if (rr < NROLE) r = (int)rr;
      }
    }
    roleL = r;
  }
  __syncthreads();
  const int b = roleL;
  if (b < 0) return;

  if (b < KS) {
    // ================= SENDER =================
    const int p    = w & 3;
    const int lr   = ((w >> 2) << 6) + lane;   // 0..127
    const bool gact = (lr < 100);
    const int gi   = lr / 25, rr = lr % 25;
    const int grow = gi * 250 + b * RPB + rr;  // global gate row

    float whh[64], wih[10], bsum = 0.f;
    if (gact) {
      #pragma unroll
      for (int i = 0; i < 64; i++) {
        int k = p * 64 + i;
        whh[i] = (k < HS) ? W_hh1[(size_t)grow * HS + k] : 0.f;
      }
      #pragma unroll
      for (int i = 0; i < 10; i++) wih[i] = W_ih1[grow * VOC + p * 10 + i];
      bsum = b_ih1[grow] + b_hh1[grow];
    }
    // wave 0: W_p slice (lane j holds W_p[j, b*25 .. +25))
    float wps[RPB];
    if (w == 0) {
      #pragma unroll
      for (int r = 0; r < RPB; r++)
        wps[r] = (lane < VOC) ? W_p[lane * HS + b * RPB + r] : 0.f;
    }
    const float bpv = (lane < VOC) ? b_p[lane] : 0.f;   // all waves (softmax)

    // ---- pre-step: h0 = relu(W_s1 @ x + b_s1), this block's 25 rows ----
    {
      const int nr = (w == 7) ? 4 : 3;
      for (int j = 0; j < nr; ++j) {
        const int r = 3 * w + j;
        const float4* wr = (const float4*)(W_s1 + (size_t)(b * RPB + r) * 4096);
        const float4* xr = (const float4*)x;
        float a0 = 0.f, a1 = 0.f, a2 = 0.f, a3 = 0.f;
        #pragma unroll
        for (int q = 0; q < 16; ++q) {
          float4 w4 = wr[lane + (q << 6)], x4 = xr[lane + (q << 6)];
          a0 += w4.x * x4.x; a1 += w4.y * x4.y; a2 += w4.z * x4.z; a3 += w4.w * x4.w;
        }
        float acc = (a0 + a1) + (a2 + a3);
        #pragma unroll
        for (int o = 32; o; o >>= 1) acc += __shfl_down(acc, o);
        if (lane == 0) h0L[r] = acc + b_s1[b * RPB + r];
      }
    }
    __syncthreads();
    if (w == 0 && lane < RPB) {    // publish h(0), tag 1 (parity 1), dual
      float hn0 = fmaxf(h0L[lane], 0.f);
      ull wv = packtv(1u, hn0);
      st_l2(&PKNH(ws, 1)[b * RPB + lane], wv);
      st_llc(&PKNHS(ws, 1)[b * RPB + lane], wv);
    }

    float c  = 0.f;   // cell state, wave0 lanes<25
    float sv = 0.f;   // current symbol, lane-distributed
    bool useLLC = false;                  // sticky fallback (wave0-uniform)
    int  strikes = 0;
    const bool h3v = (192 + lane) < HS;   // lane < 58
    const bool l6v = lane < (400 - 384);  // lane < 16

    for (int s = 0; s <= TMAX; ++s) {
      float gv = 0.f;
      if (s > 0 && lane < VOC) gv = gum[(s - 1) * VOC + lane];

      // ---- wave-0-only merged spin: h(s) + lp(s-1..), tag s+1 ----
      if (w == 0) {
        const unsigned need = (unsigned)(s + 1);
        const int par = (s + 1) & 1;
        const bool lpact = (s > 0);
        const ull* nhp  = PKNH(ws, par);   const ull* lpp  = PKLP(ws, par);
        const ull* nhps = PKNHS(ws, par);  const ull* lpps = PKLPS(ws, par);
        ull hw0, hw1, hw2, hw3, lw0, lw1, lw2, lw3, lw4, lw5, lw6;
        int spins = 0;
        bool got = false;
        while (!got) {
          bool viaShadow = useLLC;
          if (!useLLC) {
            const ull* pn0 = nhp + lane;        const ull* pn1 = nhp + 64 + lane;
            const ull* pn2 = nhp + 128 + lane;  const ull* pn3 = nhp + 192 + lane;
            const ull* pl0 = lpp + lane;        const ull* pl1 = lpp + 64 + lane;
            const ull* pl2 = lpp + 128 + lane;  const ull* pl3 = lpp + 192 + lane;
            const ull* pl4 = lpp + 256 + lane;  const ull* pl5 = lpp + 320 + lane;
            const ull* pl6 = lpp + 384 + lane;
            POLL11("sc0");
            if (__all(TAGOK())) got = true;
            else if (++spins > SPIN_CAP) { viaShadow = true; spins = 0; }
          }
          if (!got && viaShadow) {
            const ull* pn0 = nhps + lane;        const ull* pn1 = nhps + 64 + lane;
            const ull* pn2 = nhps + 128 + lane;  const ull* pn3 = nhps + 192 + lane;
            const ull* pl0 = lpps + lane;        const ull* pl1 = lpps + 64 + lane;
            const ull* pl2 = lpps + 128 + lane;  const ull* pl3 = lpps + 192 + lane;
            const ull* pl4 = lpps + 256 + lane;  const ull* pl5 = lpps + 320 + lane;
            const ull* pl6 = lpps + 384 + lane;
            POLL11("sc0 sc1");
            if (__all(TAGOK())) {
              got = true;
              if (!useLLC && ++strikes >= 2) useLLC = true;  // primary proven stale
            }
          }
        }
        hx[lane] = lowf(hw0); hx[64 + lane] = lowf(hw1); hx[128 + lane] = lowf(hw2);
        if (h3v) hx[192 + lane] = lowf(hw3);
        if (lpact) {
          lpx[lane] = lowf(lw0);        lpx[64 + lane] = lowf(lw1);
          lpx[128 + lane] = lowf(lw2);  lpx[192 + lane] = lowf(lw3);
          lpx[256 + lane] = lowf(lw4);  lpx[320 + lane] = lowf(lw5);
          if (l6v) lpx[384 + lane] = lowf(lw6);
        }
      }
      __syncthreads();   // #2: broadcast hx/lpx

      float hv0 = hx[lane], hv1 = hx[64 + lane], hv2 = hx[128 + lane];
      float hv3 = h3v ? hx[192 + lane] : 0.f;

      // ---- per-wave softmax of step s-1 (redundant across waves) ----
      if (s > 0) {
        float lg = -INFINITY;
        if (lane < VOC) {
          float acc = bpv + gv;
          #pragma unroll
          for (int m = 0; m < KS; ++m) acc += lpx[m * VOC + lane];
          lg = acc;
        }
        float v = lg; int bi = lane;
        #pragma unroll
        for (int o = 32; o; o >>= 1) {      // first-max argmax (ties -> lower lane)
          float ov = __shfl_down(v, o);
          int   oi = __shfl_down(bi, o);
          if (ov > v) { v = ov; bi = oi; }
        }
        float m  = __shfl(v, 0);
        int  idx = __shfl(bi, 0);
        float e = (lane < VOC) ? expf(lg - m) : 0.f;
        float ssum = e;
        #pragma unroll
        for (int o = 32; o; o >>= 1) ssum += __shfl_down(ssum, o);
        ssum = __shfl(ssum, 0);
        float soft = e / ssum;
        float hard = (lane == idx) ? 1.f : 0.f;
        float st   = (hard + soft) - soft;           // exact ST forward ordering
        const bool last = (s - 1 == TMAX - 1);
        float emit = last ? ((lane == VOC - 1) ? 1.f : 0.f) : st;
        const bool done = (idx == VOC - 1) || last;
        if (b == 0 && w == 0 && lane < VOC) {
          ull mv_ = packtv((unsigned)s | (done ? 0x10000u : 0u), emit);
          st_l2(&PKMSG(ws)[(s - 1) * VOC + lane], mv_);
          st_llc(&PKMSGS(ws)[(s - 1) * VOC + lane], mv_);
        }
        sv = (lane < VOC) ? emit : 0.f;
        if (done) break;                             // uniform across waves/blocks
      }

      // ---- gate partials: 100 rows x k-slice, all 8 waves ----
      if (gact) {
        float a0 = bsum, a1 = 0.f, a2 = 0.f, a3 = 0.f;
        if      (p == 0) SENDER_GATES(0, hv0)
        else if (p == 1) SENDER_GATES(1, hv1)
        else if (p == 2) SENDER_GATES(2, hv2)
        else             SENDER_GATES(3, hv3)
        part[p * 100 + lr] = (a0 + a1) + (a2 + a3);
      }
      __syncthreads();   // #1

      // ---- wave-0: reduce, h/c update, logit partial, publish tag s+2 ----
      if (w == 0) {
        float gi_ = RED(lane < RPB ? lane : 0);
        float gf_ = RED(25 + (lane < RPB ? lane : 0));
        float gg_ = RED(50 + (lane < RPB ? lane : 0));
        float go_ = RED(75 + (lane < RPB ? lane : 0));
        float ig = sigf(gi_), fg = sigf(gf_), gg = tanhf(gg_), og = sigf(go_);
        float cn = fg * c + ig * gg; c = cn;
        float hn = og * tanhf(cn);
        float lpsum = 0.f;
        #pragma unroll
        for (int r = 0; r < RPB; ++r) lpsum += wps[r] * lanebc(hn, r);
        const unsigned nt = (unsigned)(s + 2);
        const int np = (s + 2) & 1;
        if (lane < RPB) {
          ull wv = packtv(nt, hn);
          st_l2(&PKNH(ws, np)[b * RPB + lane], wv);
          st_llc(&PKNHS(ws, np)[b * RPB + lane], wv);
        }
        if (lane < VOC) {
          ull wl = packtv(nt, lpsum);
          st_l2(&PKLP(ws, np)[b * VOC + lane], wl);
          st_llc(&PKLPS(ws, np)[b * VOC + lane], wl);
        }
      }
    }
  } else {
    // ================= RECEIVER (concurrent consumer) =================
    const bool act = (t0 < 400);
    float wih2[VOC], whh2[HRr], bsum2 = 0.f;
    if (act) {
      #pragma unroll
      for (int i = 0; i < VOC; i++) wih2[i] = W_ih2[t0 * VOC + i];
      #pragma unroll
      for (int i = 0; i < HRr; i++) whh2[i] = W_hh2[t0 * HRr + i];
      bsum2 = b_ih2[t0] + b_hh2[t0];
    }
    float c2 = 0.f, rv0 = 0.f, rv1 = 0.f;
    bool useLLC = false;
    int  strikes = 0;

    for (int t = 0; t < TMAX; ++t) {
      // ---- wave-0-only spin on tagged message words ----
      if (w == 0) {
        const bool mv = (lane < VOC);
        const unsigned need = (unsigned)(t + 1);
        ull mw = 0;
        int spins = 0;
        for (;;) {
          if (!useLLC) {
            if (mv) mw = ld_l2(&PKMSG(ws)[t * VOC + lane]);
            bool ok = !mv || ((unsigned)(mw >> 32) & 0xFFFFu) == need;
            if (__all(ok)) break;
            if (++spins > SPIN_CAP_R) {
              if (mv) mw = ld_llc(&PKMSGS(ws)[t * VOC + lane]);
              bool ok2 = !mv || ((unsigned)(mw >> 32) & 0xFFFFu) == need;
              if (__all(ok2)) { if (++strikes >= 2) useLLC = true; break; }
              spins = 0;
            }
          } else {
            if (mv) mw = ld_llc(&PKMSGS(ws)[t * VOC + lane]);
            bool ok = !mv || ((unsigned)(mw >> 32) & 0xFFFFu) == need;
            if (__all(ok)) break;
          }
        }
        if (mv) symx[lane] = lowf(mw);
        if (lane == 0) *doneLp = (int)(((unsigned)(mw >> 32)) >> 16);
      }
      __syncthreads();
      const bool done = (*doneLp != 0);
      float sv2 = (lane < VOC) ? symx[lane] : 0.f;
      if (act) {
        float a0 = bsum2, a1 = 0.f, a2 = 0.f, a3 = 0.f;
        #pragma unroll
        for (int i = 0; i < VOC; i += 4) {
          a0 += wih2[i    ] * lanebc(sv2, i    );
          a1 += wih2[i + 1] * lanebc(sv2, i + 1);
          a2 += wih2[i + 2] * lanebc(sv2, i + 2);
          a3 += wih2[i + 3] * lanebc(sv2, i + 3);
        }
        #pragma unroll
        for (int i = 0; i < 64; i += 4) {
          a0 += whh2[i    ] * lanebc(rv0, i    );
          a1 += whh2[i + 1] * lanebc(rv0, i + 1);
          a2 += whh2[i + 2] * lanebc(rv0, i + 2);
          a3 += whh2[i + 3] * lanebc(rv0, i + 3);
        }
        #pragma unroll
        for (int i = 0; i < 36; i += 4) {
          a0 += whh2[64 + i    ] * lanebc(rv1, i    );
          a1 += whh2[64 + i + 1] * lanebc(rv1, i + 1);
          a2 += whh2[64 + i + 2] * lanebc(rv1, i + 2);
          a3 += whh2[64 + i + 3] * lanebc(rv1, i + 3);
        }
        gL[t0] = (a0 + a1) + (a2 + a3);
      }
      __syncthreads();
      if (t0 < HRr) {
        float ig = sigf(gL[t0]);
        float fg = sigf(gL[100 + t0]);
        float gg = tanhf(gL[200 + t0]);
        float og = sigf(gL[300 + t0]);
        float cn = fg * c2 + ig * gg; c2 = cn;
        hL[t0] = og * tanhf(cn);
      }
      __syncthreads();
      rv0 = hL[lane];
      rv1 = (lane < 36) ? hL[64 + lane] : 0.f;
      if (done) break;
    }
    if (t0 < HRr) ws[WS_HR + t0] = hL[t0];
  }
}

// ---------------- kernel 2: logits + exp + partial sums (105 MB HBM) -------
__global__ __launch_bounds__(256) void k_out(
    const float* __restrict__ W_r, const float* __restrict__ b_r,
    float* __restrict__ ws, float* __restrict__ out) {
  __shared__ float4 h4[25];
  __shared__ float  red[4];
  const int t0 = threadIdx.x;
  if (t0 < 25) h4[t0] = ((const float4*)(ws + WS_HR))[t0];
  __syncthreads();
  const int lane = t0 & 63;
  const int wv   = t0 >> 6;
  const int sl   = lane & 31;
  const int hf   = lane >> 5;
  const int base = blockIdx.x * 128 + wv * 32;
  float accs = 0.f;
  #pragma unroll 4
  for (int i = 0; i < 16; ++i) {
    const int row = base + 2 * i + hf;
    float v = 0.f;
    if (sl < 25) {
      float4 w4 = ((const float4*)W_r)[(size_t)row * 25 + sl];
      float4 hq = h4[sl];
      v = w4.x * hq.x + w4.y * hq.y + w4.z * hq.z + w4.w * hq.w;
    }
    #pragma unroll
    for (int o = 16; o; o >>= 1) v += __shfl_down(v, o, 32);
    float e = 0.f;
    if (sl == 0) { e = expf(v + b_r[row]); accs += e; }
    float eB = __shfl(e, 32);
    if (lane == 0) ((float2*)out)[(base + 2 * i) >> 1] = make_float2(e, eB);
  }
  accs += __shfl_down(accs, 32);     // lane0 += lane32
  if (lane == 0) red[wv] = accs;
  __syncthreads();
  if (t0 == 0)
    atomicAdd(&ws[WS_SUMS + (blockIdx.x & 63)], (red[0] + red[1]) + (red[2] + red[3]));
}

// ---------------- kernel 3: out *= 1/sum -----------------------------------
__global__ __launch_bounds__(256) void k_scale(const float* __restrict__ ws,
                                               float* __restrict__ out) {
  float s = ws[WS_SUMS + (threadIdx.x & 63)];
  #pragma unroll
  for (int o = 1; o < 64; o <<= 1) s += __shfl_xor(s, o);   // identical all lanes
  const float rinv = 1.f / s;
  const int i = blockIdx.x * 256 + threadIdx.x;   // float4 index
  float4 e = ((const float4*)out)[i];
  e.x *= rinv; e.y *= rinv; e.z *= rinv; e.w *= rinv;
  ((float4*)out)[i] = e;
}

extern "C" void kernel_launch(void* const* d_in, const int* in_sizes, int n_in,
                              void* d_out, int out_size, void* d_ws, size_t ws_size,
                              hipStream_t stream) {
  const float* x     = (const float*)d_in[0];
  const float* gum   = (const float*)d_in[1];
  const float* W_s1  = (const float*)d_in[2];
  const float* b_s1  = (const float*)d_in[3];
  const float* W_ih1 = (const float*)d_in[4];
  const float* W_hh1 = (const float*)d_in[5];
  const float* b_ih1 = (const float*)d_in[6];
  const float* b_hh1 = (const float*)d_in[7];
  const float* W_p   = (const float*)d_in[8];
  const float* b_p   = (const float*)d_in[9];
  const float* W_ih2 = (const float*)d_in[10];
  const float* W_hh2 = (const float*)d_in[11];
  const float* b_ih2 = (const float*)d_in[12];
  const float* b_hh2 = (const float*)d_in[13];
  const float* W_r   = (const float*)d_in[14];
  const float* b_r   = (const float*)d_in[15];
  float* ws  = (float*)d_ws;
  float* out = (float*)d_out;

  // zero packed tag regions (primary + shadow) + sums + ctrl
  (void)hipMemsetAsync(d_ws, 0, WS_ZERO_BYTES, stream);
  k_sender<<<GRID_SENDER, 512, 0, stream>>>(x, W_s1, b_s1, gum, W_ih1, W_hh1,
                                            b_ih1, b_hh1, W_p, b_p,
                                            W_ih2, W_hh2, b_ih2, b_hh2, ws);
  k_out   <<<NCLS/128, 256, 0, stream>>>(W_r, b_r, ws, out);
  k_scale <<<NCLS/1024,256, 0, stream>>>(ws, out);
}

// Round 11
// 329.148 us; speedup vs baseline: 1.1736x; 1.1736x over previous
//
#include <hip/hip_runtime.h>
#include <math.h>

// Problem constants (from reference)
#define HS    250      // sender hidden
#define HRr   100      // receiver hidden
#define VOC   40       // vocab, EOS = 39
#define TMAX  30       // max message length
#define NCLS  262144   // output classes
#define KS    10       // sender blocks (each owns 25 h-rows = 100 gate rows)
#define RPB   25       // h-rows per sender block

typedef unsigned long long ull;

// ws layout. Packed (tag<<32 | float) regions first, 8B-aligned:
//   PK_NH : ull[2][256]  h exchange, double-buffered by tag parity
//   (legacy lp region [512,1312) unused — offsets kept stable)
//   PK_MSG: ull[30*40]   @ ull 1312, message symbols (tag carries done bit)
// Floats after: WS_SUMS float[64] @byte 20096; WS_HR float[100] @byte 20352.
#define PKNH(wsp, par) ((ull*)(wsp) + (size_t)(par) * 256)
#define PKMSG(wsp)     ((ull*)(wsp) + 1312)
#define WS_SUMS 5024   // float index
#define WS_HR   5088   // float index (byte 20352, 16B aligned)
#define WS_ZERO_BYTES 20352

#define TG(wv) ((unsigned)((wv) >> 32))

__device__ __forceinline__ float sigf(float x) { return 1.f / (1.f + expf(-x)); }
__device__ __forceinline__ float lanebc(float v, int l) {
  return __int_as_float(__builtin_amdgcn_readlane(__float_as_int(v), l));
}
__device__ __forceinline__ ull packtv(unsigned tag, float v) {
  return ((ull)tag << 32) | (ull)__float_as_uint(v);
}
__device__ __forceinline__ float lowf(ull w) { return __uint_as_float((unsigned)w); }

// Exchange ops: explicit sc0 sc1 (bypass L1+L2 -> served at LLC). R9-proven.
__device__ __forceinline__ void st_llc(ull* p, ull v) {
  asm volatile("global_store_dwordx2 %0, %1, off sc0 sc1"
               :: "v"(p), "v"(v) : "memory");
}
__device__ __forceinline__ ull ld_llc(const ull* p) {
  ull r;
  asm volatile("global_load_dwordx2 %0, %1, off sc0 sc1\n\t"
               "s_waitcnt vmcnt(0)"
               : "=v"(r) : "v"(p) : "memory");
  return r;
}

#define SENDER_GATES(P, HV)                                   \
  {                                                           \
    _Pragma("unroll")                                         \
    for (int i = 0; i < 64; i += 4) {                         \
      a0 += whh[i    ] * lanebc(HV, i    );                   \
      a1 += whh[i + 1] * lanebc(HV, i + 1);                   \
      a2 += whh[i + 2] * lanebc(HV, i + 2);                   \
      a3 += whh[i + 3] * lanebc(HV, i + 3);                   \
    }                                                         \
    _Pragma("unroll")                                         \
    for (int i = 0; i < 10; i += 2) {                         \
      a0 += wih[i    ] * lanebc(sv, (P) * 10 + i    );        \
      a1 += wih[i + 1] * lanebc(sv, (P) * 10 + i + 1);        \
    }                                                         \
  }

#define RED(x) ((part[(x)] + part[100 + (x)]) + (part[200 + (x)] + part[300 + (x)]))

// ---------------- kernel 1: h0 + sender (blocks 0..9) + receiver (10) ------
// R9 structure MINUS the lp exchange: every block polls the full h anyway,
// so all 40 logits are computed LOCALLY (wave w owns rows 5w..5w+4, 20 VGPR
// of W_p each). Exchange per step shrinks: publish 65->25 words, poll 11->4
// words. launch_bounds(512,1): VGPR cap 256 so the +20 wpv regs can't spill
// (R3/R6 lesson); only 11 blocks, occupancy irrelevant.
__global__ __launch_bounds__(512, 1) void k_sender(
    const float* __restrict__ x,
    const float* __restrict__ W_s1,  const float* __restrict__ b_s1,
    const float* __restrict__ gum,
    const float* __restrict__ W_ih1, const float* __restrict__ W_hh1,
    const float* __restrict__ b_ih1, const float* __restrict__ b_hh1,
    const float* __restrict__ W_p,   const float* __restrict__ b_p,
    const float* __restrict__ W_ih2, const float* __restrict__ W_hh2,
    const float* __restrict__ b_ih2, const float* __restrict__ b_hh2,
    float* __restrict__ ws) {
  __shared__ float part[400];
  __shared__ float h0L[32];
  __shared__ float hx[256];      // wave-0 broadcast of exchanged h
  __shared__ float logitsL[40];  // locally-computed logits (replaces lpx)
  __shared__ float symx[VOC];    // receiver
  __shared__ int   doneL;        // receiver
  __shared__ float gL[400];      // receiver
  __shared__ float hL[HRr];      // receiver

  const int b    = blockIdx.x;
  const int t0   = threadIdx.x;
  const int lane = t0 & 63;
  const int w    = t0 >> 6;

  if (b < KS) {
    // ================= SENDER =================
    const int p    = w & 3;
    const int lr   = ((w >> 2) << 6) + lane;   // 0..127
    const bool gact = (lr < 100);
    const int gi   = lr / 25, rr = lr % 25;
    const int grow = gi * 250 + b * RPB + rr;  // global gate row

    float whh[64], wih[10], bsum = 0.f;
    if (gact) {
      #pragma unroll
      for (int i = 0; i < 64; i++) {
        int k = p * 64 + i;
        whh[i] = (k < HS) ? W_hh1[(size_t)grow * HS + k] : 0.f;
      }
      #pragma unroll
      for (int i = 0; i < 10; i++) wih[i] = W_ih1[grow * VOC + p * 10 + i];
      bsum = b_ih1[grow] + b_hh1[grow];
    }
    const bool h3v = (192 + lane) < HS;   // lane < 58

    // W_p ownership: wave w holds rows 5w..5w+4, 4 k-strips per lane.
    float wpv[5][4];
    {
      const int row0 = 5 * w;
      #pragma unroll
      for (int r = 0; r < 5; ++r) {
        const float* wr = W_p + (size_t)(row0 + r) * HS;
        wpv[r][0] = wr[lane];
        wpv[r][1] = wr[64 + lane];
        wpv[r][2] = wr[128 + lane];
        wpv[r][3] = h3v ? wr[192 + lane] : 0.f;
      }
    }
    const float bpv = (lane < VOC) ? b_p[lane] : 0.f;   // all waves (softmax)

    // ---- pre-step: h0 = relu(W_s1 @ x + b_s1), this block's 25 rows ----
    {
      const int nr = (w == 7) ? 4 : 3;
      for (int j = 0; j < nr; ++j) {
        const int r = 3 * w + j;
        const float4* wr = (const float4*)(W_s1 + (size_t)(b * RPB + r) * 4096);
        const float4* xr = (const float4*)x;
        float a0 = 0.f, a1 = 0.f, a2 = 0.f, a3 = 0.f;
        #pragma unroll
        for (int q = 0; q < 16; ++q) {
          float4 w4 = wr[lane + (q << 6)], x4 = xr[lane + (q << 6)];
          a0 += w4.x * x4.x; a1 += w4.y * x4.y; a2 += w4.z * x4.z; a3 += w4.w * x4.w;
        }
        float acc = (a0 + a1) + (a2 + a3);
        #pragma unroll
        for (int o = 32; o; o >>= 1) acc += __shfl_down(acc, o);
        if (lane == 0) h0L[r] = acc + b_s1[b * RPB + r];
      }
    }
    __syncthreads();
    if (w == 0 && lane < RPB) {    // publish h(0), tag 1 (parity 1)
      float hn0 = fmaxf(h0L[lane], 0.f);
      st_llc(&PKNH(ws, 1)[b * RPB + lane], packtv(1u, hn0));
    }

    float c  = 0.f;   // cell state, wave0 lanes<25
    float sv = 0.f;   // current symbol, lane-distributed

    for (int s = 0; s <= TMAX; ++s) {
      float gv = 0.f;
      if (s > 0 && lane < VOC) gv = gum[(s - 1) * VOC + lane];

      // ---- wave-0-only spin: h(s), tag s+1 — only 4 words now ----
      if (w == 0) {
        const unsigned need = (unsigned)(s + 1);
        const int par = (s + 1) & 1;
        const ull* nhp = PKNH(ws, par);
        const ull* pn0 = nhp + lane;        const ull* pn1 = nhp + 64 + lane;
        const ull* pn2 = nhp + 128 + lane;  const ull* pn3 = nhp + 192 + lane;
        ull hw0, hw1, hw2, hw3;
        for (;;) {
          asm volatile(
            "global_load_dwordx2 %0, %4, off sc0 sc1\n\t"
            "global_load_dwordx2 %1, %5, off sc0 sc1\n\t"
            "global_load_dwordx2 %2, %6, off sc0 sc1\n\t"
            "global_load_dwordx2 %3, %7, off sc0 sc1\n\t"
            "s_waitcnt vmcnt(0)"
            : "=&v"(hw0), "=&v"(hw1), "=&v"(hw2), "=&v"(hw3)
            : "v"(pn0), "v"(pn1), "v"(pn2), "v"(pn3)
            : "memory");
          bool ok = TG(hw0) == need && TG(hw1) == need && TG(hw2) == need &&
                    (!h3v || TG(hw3) == need);
          if (__all(ok)) break;
        }
        hx[lane] = lowf(hw0); hx[64 + lane] = lowf(hw1); hx[128 + lane] = lowf(hw2);
        if (h3v) hx[192 + lane] = lowf(hw3);
      }
      __syncthreads();   // #2: broadcast hx

      float hv0 = hx[lane], hv1 = hx[64 + lane], hv2 = hx[128 + lane];
      float hv3 = h3v ? hx[192 + lane] : 0.f;

      // ---- per-wave softmax of step s-1 (logits computed locally) ----
      if (s > 0) {
        // local logits: wave w computes rows 5w..5w+4 of W_p @ h
        #pragma unroll
        for (int r = 0; r < 5; ++r) {
          float pp = (wpv[r][0] * hv0 + wpv[r][1] * hv1) +
                     (wpv[r][2] * hv2 + wpv[r][3] * hv3);
          #pragma unroll
          for (int o = 32; o; o >>= 1) pp += __shfl_down(pp, o);
          if (lane == 0) logitsL[5 * w + r] = pp;
        }
        __syncthreads();   // #3: logits ready

        float lg = -INFINITY;
        if (lane < VOC) lg = bpv + gv + logitsL[lane];
        float v = lg; int bi = lane;
        #pragma unroll
        for (int o = 32; o; o >>= 1) {      // first-max argmax (ties -> lower lane)
          float ov = __shfl_down(v, o);
          int   oi = __shfl_down(bi, o);
          if (ov > v) { v = ov; bi = oi; }
        }
        float m  = __shfl(v, 0);
        int  idx = __shfl(bi, 0);
        float e = (lane < VOC) ? expf(lg - m) : 0.f;
        float ssum = e;
        #pragma unroll
        for (int o = 32; o; o >>= 1) ssum += __shfl_down(ssum, o);
        ssum = __shfl(ssum, 0);
        float soft = e / ssum;
        float hard = (lane == idx) ? 1.f : 0.f;
        float st   = (hard + soft) - soft;           // exact ST forward ordering
        const bool last = (s - 1 == TMAX - 1);
        float emit = last ? ((lane == VOC - 1) ? 1.f : 0.f) : st;
        const bool done = (idx == VOC - 1) || last;
        if (b == 0 && w == 0 && lane < VOC)
          st_llc(&PKMSG(ws)[(s - 1) * VOC + lane],
                 packtv((unsigned)s | (done ? 0x10000u : 0u), emit));
        sv = (lane < VOC) ? emit : 0.f;
        if (done) break;                             // uniform across waves/blocks
      }

      // ---- gate partials: 100 rows x k-slice, all 8 waves ----
      if (gact) {
        float a0 = bsum, a1 = 0.f, a2 = 0.f, a3 = 0.f;
        if      (p == 0) SENDER_GATES(0, hv0)
        else if (p == 1) SENDER_GATES(1, hv1)
        else if (p == 2) SENDER_GATES(2, hv2)
        else             SENDER_GATES(3, hv3)
        part[p * 100 + lr] = (a0 + a1) + (a2 + a3);
      }
      __syncthreads();   // #1

      // ---- wave-0: reduce, h/c update, publish h tag s+2 (no lp!) ----
      if (w == 0) {
        float gi_ = RED(lane < RPB ? lane : 0);
        float gf_ = RED(25 + (lane < RPB ? lane : 0));
        float gg_ = RED(50 + (lane < RPB ? lane : 0));
        float go_ = RED(75 + (lane < RPB ? lane : 0));
        float ig = sigf(gi_), fg = sigf(gf_), gg = tanhf(gg_), og = sigf(go_);
        float cn = fg * c + ig * gg; c = cn;
        float hn = og * tanhf(cn);
        const unsigned nt = (unsigned)(s + 2);
        const int np = (s + 2) & 1;
        if (lane < RPB) st_llc(&PKNH(ws, np)[b * RPB + lane], packtv(nt, hn));
      }
    }
  } else {
    // ================= RECEIVER (concurrent consumer) =================
    const bool act = (t0 < 400);
    float wih2[VOC], whh2[HRr], bsum2 = 0.f;
    if (act) {
      #pragma unroll
      for (int i = 0; i < VOC; i++) wih2[i] = W_ih2[t0 * VOC + i];
      #pragma unroll
      for (int i = 0; i < HRr; i++) whh2[i] = W_hh2[t0 * HRr + i];
      bsum2 = b_ih2[t0] + b_hh2[t0];
    }
    float c2 = 0.f, rv0 = 0.f, rv1 = 0.f;

    for (int t = 0; t < TMAX; ++t) {
      // ---- wave-0-only spin on tagged message words ----
      if (w == 0) {
        const bool mv = (lane < VOC);
        ull mw = 0;
        for (;;) {
          if (mv) mw = ld_llc(&PKMSG(ws)[t * VOC + lane]);
          bool ok = !mv || ((unsigned)(mw >> 32) & 0xFFFFu) == (unsigned)(t + 1);
          if (__all(ok)) break;
        }
        if (mv) symx[lane] = lowf(mw);
        if (lane == 0) doneL = (int)(((unsigned)(mw >> 32)) >> 16);
      }
      __syncthreads();
      const bool done = (doneL != 0);
      float sv2 = (lane < VOC) ? symx[lane] : 0.f;
      if (act) {
        float a0 = bsum2, a1 = 0.f, a2 = 0.f, a3 = 0.f;
        #pragma unroll
        for (int i = 0; i < VOC; i += 4) {
          a0 += wih2[i    ] * lanebc(sv2, i    );
          a1 += wih2[i + 1] * lanebc(sv2, i + 1);
          a2 += wih2[i + 2] * lanebc(sv2, i + 2);
          a3 += wih2[i + 3] * lanebc(sv2, i + 3);
        }
        #pragma unroll
        for (int i = 0; i < 64; i += 4) {
          a0 += whh2[i    ] * lanebc(rv0, i    );
          a1 += whh2[i + 1] * lanebc(rv0, i + 1);
          a2 += whh2[i + 2] * lanebc(rv0, i + 2);
          a3 += whh2[i + 3] * lanebc(rv0, i + 3);
        }
        #pragma unroll
        for (int i = 0; i < 36; i += 4) {
          a0 += whh2[64 + i    ] * lanebc(rv1, i    );
          a1 += whh2[64 + i + 1] * lanebc(rv1, i + 1);
          a2 += whh2[64 + i + 2] * lanebc(rv1, i + 2);
          a3 += whh2[64 + i + 3] * lanebc(rv1, i + 3);
        }
        gL[t0] = (a0 + a1) + (a2 + a3);
      }
      __syncthreads();
      if (t0 < HRr) {
        float ig = sigf(gL[t0]);
        float fg = sigf(gL[100 + t0]);
        float gg = tanhf(gL[200 + t0]);
        float og = sigf(gL[300 + t0]);
        float cn = fg * c2 + ig * gg; c2 = cn;
        hL[t0] = og * tanhf(cn);
      }
      __syncthreads();
      rv0 = hL[lane];
      rv1 = (lane < 36) ? hL[64 + lane] : 0.f;
      if (done) break;
    }
    if (t0 < HRr) ws[WS_HR + t0] = hL[t0];
  }
}

// ---------------- kernel 2: logits + exp + partial sums (105 MB HBM) -------
__global__ __launch_bounds__(256) void k_out(
    const float* __restrict__ W_r, const float* __restrict__ b_r,
    float* __restrict__ ws, float* __restrict__ out) {
  __shared__ float4 h4[25];
  __shared__ float  red[4];
  const int t0 = threadIdx.x;
  if (t0 < 25) h4[t0] = ((const float4*)(ws + WS_HR))[t0];
  __syncthreads();
  const int lane = t0 & 63;
  const int wv   = t0 >> 6;
  const int sl   = lane & 31;
  const int hf   = lane >> 5;
  const int base = blockIdx.x * 128 + wv * 32;
  float accs = 0.f;
  #pragma unroll 4
  for (int i = 0; i < 16; ++i) {
    const int row = base + 2 * i + hf;
    float v = 0.f;
    if (sl < 25) {
      float4 w4 = ((const float4*)W_r)[(size_t)row * 25 + sl];
      float4 hq = h4[sl];
      v = w4.x * hq.x + w4.y * hq.y + w4.z * hq.z + w4.w * hq.w;
    }
    #pragma unroll
    for (int o = 16; o; o >>= 1) v += __shfl_down(v, o, 32);
    float e = 0.f;
    if (sl == 0) { e = expf(v + b_r[row]); accs += e; }
    float eB = __shfl(e, 32);
    if (lane == 0) ((float2*)out)[(base + 2 * i) >> 1] = make_float2(e, eB);
  }
  accs += __shfl_down(accs, 32);     // lane0 += lane32
  if (lane == 0) red[wv] = accs;
  __syncthreads();
  if (t0 == 0)
    atomicAdd(&ws[WS_SUMS + (blockIdx.x & 63)], (red[0] + red[1]) + (red[2] + red[3]));
}

// ---------------- kernel 3: out *= 1/sum -----------------------------------
__global__ __launch_bounds__(256) void k_scale(const float* __restrict__ ws,
                                               float* __restrict__ out) {
  float s = ws[WS_SUMS + (threadIdx.x & 63)];
  #pragma unroll
  for (int o = 1; o < 64; o <<= 1) s += __shfl_xor(s, o);   // identical all lanes
  const float rinv = 1.f / s;
  const int i = blockIdx.x * 256 + threadIdx.x;   // float4 index
  float4 e = ((const float4*)out)[i];
  e.x *= rinv; e.y *= rinv; e.z *= rinv; e.w *= rinv;
  ((float4*)out)[i] = e;
}

extern "C" void kernel_launch(void* const* d_in, const int* in_sizes, int n_in,
                              void* d_out, int out_size, void* d_ws, size_t ws_size,
                              hipStream_t stream) {
  const float* x     = (const float*)d_in[0];
  const float* gum   = (const float*)d_in[1];
  const float* W_s1  = (const float*)d_in[2];
  const float* b_s1  = (const float*)d_in[3];
  const float* W_ih1 = (const float*)d_in[4];
  const float* W_hh1 = (const float*)d_in[5];
  const float* b_ih1 = (const float*)d_in[6];
  const float* b_hh1 = (const float*)d_in[7];
  const float* W_p   = (const float*)d_in[8];
  const float* b_p   = (const float*)d_in[9];
  const float* W_ih2 = (const float*)d_in[10];
  const float* W_hh2 = (const float*)d_in[11];
  const float* b_ih2 = (const float*)d_in[12];
  const float* b_hh2 = (const float*)d_in[13];
  const float* W_r   = (const float*)d_in[14];
  const float* b_r   = (const float*)d_in[15];
  float* ws  = (float*)d_ws;
  float* out = (float*)d_out;

  // zero packed tag regions + sum slots (ws re-poisoned 0xAA every launch)
  (void)hipMemsetAsync(d_ws, 0, WS_ZERO_BYTES, stream);
  k_sender<<<KS + 1,   512, 0, stream>>>(x, W_s1, b_s1, gum, W_ih1, W_hh1,
                                         b_ih1, b_hh1, W_p, b_p,
                                         W_ih2, W_hh2, b_ih2, b_hh2, ws);
  k_out   <<<NCLS/128, 256, 0, stream>>>(W_r, b_r, ws, out);
  k_scale <<<NCLS/1024,256, 0, stream>>>(ws, out);
}